// Round 1
// baseline (765.949 us; speedup 1.0000x reference)
//
#include <hip/hip_runtime.h>
#include <type_traits>

// Problem constants: H=16, D=64, DM=1024, L=256, B=64, CHUNK=64, SCALE=1/8.

typedef short v8s __attribute__((ext_vector_type(8)));
typedef float v4f __attribute__((ext_vector_type(4)));

__device__ __forceinline__ float bf2f(short s) {
    unsigned int u = ((unsigned int)(unsigned short)s) << 16;
    float f;
    __builtin_memcpy(&f, &u, 4);
    return f;
}
__device__ __forceinline__ short f2bf(float f) {
    unsigned int u;
    __builtin_memcpy(&u, &f, 4);
    u = u + 0x7fffu + ((u >> 16) & 1u);   // RNE
    return (short)(u >> 16);
}

// ---------------- fp32 -> bf16 conversion (vectorized x4) ----------------
__global__ void __launch_bounds__(256)
cvt_bf16(const float* __restrict__ in, short* __restrict__ out, int n4) {
    int i = blockIdx.x * 256 + threadIdx.x;
    if (i >= n4) return;
    float4 v = ((const float4*)in)[i];
    short4 o;
    o.x = f2bf(v.x); o.y = f2bf(v.y); o.z = f2bf(v.z); o.w = f2bf(v.w);
    ((short4*)out)[i] = o;
}

// ---------------- bf16 MFMA GEMM:  C[M,N] = A[M,K] * B[N,K]^T ----------------
// 128x128 block tile, BK=32, 256 threads = 4 waves (2x2), each wave 64x64 (4x4
// MFMA 16x16x32 tiles). LDS padded to stride 40 bf16 to keep conflicts <=2-way.
template <typename OutT>
__global__ void __launch_bounds__(256)
gemm_nt(const short* __restrict__ A, const short* __restrict__ B,
        OutT* __restrict__ C, int M, int N, int K) {
    constexpr int BM = 128, BK = 32, LDK = 40;
    __shared__ short sA[BM * LDK];
    __shared__ short sB[BM * LDK];
    const int tid = threadIdx.x;
    const int bm = blockIdx.x, bn = blockIdx.y;
    const int lane = tid & 63, w = tid >> 6;
    const int wy = w >> 1, wx = w & 1;
    const int lr = lane & 15, lq = lane >> 4;

    v4f acc[4][4] = {};

    const int arow = tid >> 1, aseg = (tid & 1) * 16;
    const short* gA = A + (long)(bm * BM + arow) * K + aseg;
    const short* gB = B + (long)(bn * BM + arow) * K + aseg;
    short* lA = &sA[arow * LDK + aseg];
    short* lB = &sB[arow * LDK + aseg];

    for (int kt = 0; kt < K; kt += BK) {
        int4 a0 = *(const int4*)(gA + kt);
        int4 a1 = *(const int4*)(gA + kt + 8);
        int4 b0 = *(const int4*)(gB + kt);
        int4 b1 = *(const int4*)(gB + kt + 8);
        __syncthreads();
        *(int4*)lA = a0; *(int4*)(lA + 8) = a1;
        *(int4*)lB = b0; *(int4*)(lB + 8) = b1;
        __syncthreads();
        v8s af[4], bfv[4];
#pragma unroll
        for (int i = 0; i < 4; i++)
            af[i] = *(const v8s*)&sA[(wy * 64 + i * 16 + lr) * LDK + lq * 8];
#pragma unroll
        for (int j = 0; j < 4; j++)
            bfv[j] = *(const v8s*)&sB[(wx * 64 + j * 16 + lr) * LDK + lq * 8];
#pragma unroll
        for (int i = 0; i < 4; i++)
#pragma unroll
            for (int j = 0; j < 4; j++)
                acc[i][j] = __builtin_amdgcn_mfma_f32_16x16x32_bf16(af[i], bfv[j], acc[i][j], 0, 0, 0);
    }
    // epilogue: D row=(lane>>4)*4+r, col=lane&15 within each 16x16 tile
#pragma unroll
    for (int i = 0; i < 4; i++)
#pragma unroll
        for (int j = 0; j < 4; j++)
#pragma unroll
            for (int r = 0; r < 4; r++) {
                int row = bm * BM + wy * 64 + i * 16 + lq * 4 + r;
                int col = bn * BM + wx * 64 + j * 16 + lr;
                float v = acc[i][j][r];
                if constexpr (std::is_same_v<OutT, short>)
                    C[(long)row * N + col] = f2bf(v);
                else
                    C[(long)row * N + col] = v;
            }
}

// ---------------- fast-weight scan (fp32 vector ALU this round) ----------------
// One block per (b, h, mem). qkv layout: [(l*64+b)*4096 + h*256 + {q:0,k1:64,k2:128,v:192} + d]
// LDS: q,k,v,S as bf16 (stride 66 to avoid conflicts), W fp32 (stride 65).
__global__ void __launch_bounds__(256)
fastweight(const short* __restrict__ qkv, short* __restrict__ out1, short* __restrict__ out2) {
    const int bid = blockIdx.x;
    const int mem = bid & 1, h = (bid >> 1) & 15, b = bid >> 5;
    const int tid = threadIdx.x;
    __shared__ short sq[64 * 66], sk[64 * 66], sv[64 * 66], sS[64 * 66];
    __shared__ float sW[64 * 65];
    short* outbuf = mem ? out2 : out1;
    const int koff = 64 + mem * 64;

    for (int i = tid; i < 64 * 65; i += 256) sW[i] = 0.f;

    const int r = tid >> 2, seg = (tid & 3) * 16;
    const int ty = tid >> 4, tx = tid & 15;
    const int i0 = ty * 4, j0 = tx * 4;

    for (int c = 0; c < 4; c++) {
        __syncthreads();
        // ---- stage q,k,v chunk tiles ----
        {
            const long gbase = ((long)((c * 64 + r) * 64 + b)) * 4096 + h * 256;
            const int4* gq = (const int4*)(qkv + gbase + seg);
            const int4* gk = (const int4*)(qkv + gbase + koff + seg);
            const int4* gv = (const int4*)(qkv + gbase + 192 + seg);
            int4 q0 = gq[0], q1 = gq[1];
            int4 k0 = gk[0], k1 = gk[1];
            int4 v0 = gv[0], v1 = gv[1];
            int* dq = (int*)&sq[r * 66 + seg];
            int* dk = (int*)&sk[r * 66 + seg];
            int* dv = (int*)&sv[r * 66 + seg];
            dq[0] = q0.x; dq[1] = q0.y; dq[2] = q0.z; dq[3] = q0.w;
            dq[4] = q1.x; dq[5] = q1.y; dq[6] = q1.z; dq[7] = q1.w;
            dk[0] = k0.x; dk[1] = k0.y; dk[2] = k0.z; dk[3] = k0.w;
            dk[4] = k1.x; dk[5] = k1.y; dk[6] = k1.z; dk[7] = k1.w;
            dv[0] = v0.x; dv[1] = v0.y; dv[2] = v0.z; dv[3] = v0.w;
            dv[4] = v1.x; dv[5] = v1.y; dv[6] = v1.z; dv[7] = v1.w;
        }
        __syncthreads();
        // ---- phi = (elu(x)+1) / rowsum, rows handled by one wave ----
        if (tid < 64) {
            int row = tid;
            float sum = 0.f;
            for (int d = 0; d < 64; d++) {
                float x = bf2f(sq[row * 66 + d]);
                float e = x > 0.f ? x + 1.f : __expf(x);
                sum += e;
                sq[row * 66 + d] = f2bf(e);
            }
            float inv = 1.f / sum;
            for (int d = 0; d < 64; d++)
                sq[row * 66 + d] = f2bf(bf2f(sq[row * 66 + d]) * inv);
            sum = 0.f;
            for (int d = 0; d < 64; d++) {
                float x = bf2f(sk[row * 66 + d]);
                float e = x > 0.f ? x + 1.f : __expf(x);
                sum += e;
                sk[row * 66 + d] = f2bf(e);
            }
            inv = 1.f / sum;
            for (int d = 0; d < 64; d++)
                sk[row * 66 + d] = f2bf(bf2f(sk[row * 66 + d]) * inv);
        }
        __syncthreads();
        // ---- S = (q k^T) * causal mask ----
        {
            float acc[4][4] = {{0.f}};
            for (int d = 0; d < 64; d++) {
                float a[4], bb[4];
#pragma unroll
                for (int i = 0; i < 4; i++) a[i] = bf2f(sq[(i0 + i) * 66 + d]);
#pragma unroll
                for (int j = 0; j < 4; j++) bb[j] = bf2f(sk[(j0 + j) * 66 + d]);
#pragma unroll
                for (int i = 0; i < 4; i++)
#pragma unroll
                    for (int j = 0; j < 4; j++) acc[i][j] += a[i] * bb[j];
            }
#pragma unroll
            for (int i = 0; i < 4; i++)
#pragma unroll
                for (int j = 0; j < 4; j++) {
                    float v = (j0 + j <= i0 + i) ? acc[i][j] : 0.f;
                    sS[(i0 + i) * 66 + (j0 + j)] = f2bf(v);
                }
        }
        __syncthreads();
        // ---- O = S v + q W ; write to global (bf16, short4 stores) ----
        {
            float acc[4][4] = {{0.f}};
            for (int s = 0; s < 64; s++) {
                float a[4], bb[4];
#pragma unroll
                for (int i = 0; i < 4; i++) a[i] = bf2f(sS[(i0 + i) * 66 + s]);
#pragma unroll
                for (int j = 0; j < 4; j++) bb[j] = bf2f(sv[s * 66 + j0 + j]);
#pragma unroll
                for (int i = 0; i < 4; i++)
#pragma unroll
                    for (int j = 0; j < 4; j++) acc[i][j] += a[i] * bb[j];
            }
            for (int e = 0; e < 64; e++) {
                float a[4], bb[4];
#pragma unroll
                for (int i = 0; i < 4; i++) a[i] = bf2f(sq[(i0 + i) * 66 + e]);
#pragma unroll
                for (int j = 0; j < 4; j++) bb[j] = sW[e * 65 + j0 + j];
#pragma unroll
                for (int i = 0; i < 4; i++)
#pragma unroll
                    for (int j = 0; j < 4; j++) acc[i][j] += a[i] * bb[j];
            }
#pragma unroll
            for (int i = 0; i < 4; i++) {
                long o = ((long)((c * 64 + i0 + i) * 64 + b)) * 1024 + h * 64 + j0;
                short4 pk;
                pk.x = f2bf(acc[i][0]); pk.y = f2bf(acc[i][1]);
                pk.z = f2bf(acc[i][2]); pk.w = f2bf(acc[i][3]);
                *(short4*)(outbuf + o) = pk;
            }
        }
        __syncthreads();
        // ---- W += k^T v ----
        {
            float acc[4][4] = {{0.f}};
            for (int s = 0; s < 64; s++) {
                float a[4], bb[4];
#pragma unroll
                for (int i = 0; i < 4; i++) a[i] = bf2f(sk[s * 66 + i0 + i]);
#pragma unroll
                for (int j = 0; j < 4; j++) bb[j] = bf2f(sv[s * 66 + j0 + j]);
#pragma unroll
                for (int i = 0; i < 4; i++)
#pragma unroll
                    for (int j = 0; j < 4; j++) acc[i][j] += a[i] * bb[j];
            }
#pragma unroll
            for (int i = 0; i < 4; i++)
#pragma unroll
                for (int j = 0; j < 4; j++)
                    sW[(i0 + i) * 65 + j0 + j] += acc[i][j];
        }
    }
}

// ---------------- pi0 mixture: lmix = SCALE*(p*l1 + (1-p)*l2), bf16 x8 ----------------
__global__ void __launch_bounds__(256)
mix_kernel(const short* __restrict__ l1, const short* __restrict__ l2,
           const float* __restrict__ pi0, short* __restrict__ outm) {
    long idx8 = ((long)blockIdx.x * 256 + threadIdx.x) * 8;
    int col = (int)(idx8 & 1023);
    int row = (int)(idx8 >> 10);
    int hh = col >> 6;
    int l = row >> 6;   // row = l*B + b, B=64
    float p = pi0[hh * 256 + l];
    p = fminf(fmaxf(p, 0.f), 1.f);
    float q = 1.f - p;
    union { int4 v; short s[8]; } ua, ub, uo;
    ua.v = *(const int4*)(l1 + idx8);
    ub.v = *(const int4*)(l2 + idx8);
#pragma unroll
    for (int i = 0; i < 8; i++)
        uo.s[i] = f2bf(0.125f * (p * bf2f(ua.s[i]) + q * bf2f(ub.s[i])));
    *(int4*)(outm + idx8) = uo.v;
}

// ---------------- residual + LayerNorm over DM=1024 ----------------
__global__ void __launch_bounds__(256)
ln_kernel(const float* __restrict__ h, const float* __restrict__ attn,
          const float* __restrict__ gamma, const float* __restrict__ beta,
          float* __restrict__ out) {
    const int row = blockIdx.x;
    const long base = (long)row * 1024;
    const int tid = threadIdx.x;
    float4 xh = ((const float4*)(h + base))[tid];
    float4 xa = ((const float4*)(attn + base))[tid];
    float4 x;
    x.x = xh.x + xa.x; x.y = xh.y + xa.y; x.z = xh.z + xa.z; x.w = xh.w + xa.w;
    float s = x.x + x.y + x.z + x.w;
    float s2 = x.x * x.x + x.y * x.y + x.z * x.z + x.w * x.w;
#pragma unroll
    for (int m = 32; m > 0; m >>= 1) {
        s += __shfl_xor(s, m, 64);
        s2 += __shfl_xor(s2, m, 64);
    }
    __shared__ float ps[4], ps2[4];
    int w = tid >> 6, lane = tid & 63;
    if (lane == 0) { ps[w] = s; ps2[w] = s2; }
    __syncthreads();
    s = ps[0] + ps[1] + ps[2] + ps[3];
    s2 = ps2[0] + ps2[1] + ps2[2] + ps2[3];
    float mu = s * (1.f / 1024.f);
    float var = s2 * (1.f / 1024.f) - mu * mu;
    float inv = rsqrtf(var + 1e-5f);
    float4 g = ((const float4*)gamma)[tid];
    float4 bb = ((const float4*)beta)[tid];
    float4 o;
    o.x = (x.x - mu) * inv * g.x + bb.x;
    o.y = (x.y - mu) * inv * g.y + bb.y;
    o.z = (x.z - mu) * inv * g.z + bb.z;
    o.w = (x.w - mu) * inv * g.w + bb.w;
    ((float4*)(out + base))[tid] = o;
}

extern "C" void kernel_launch(void* const* d_in, const int* in_sizes, int n_in,
                              void* d_out, int out_size, void* d_ws, size_t ws_size,
                              hipStream_t stream) {
    const float* h     = (const float*)d_in[0];
    const float* qkvw  = (const float*)d_in[1];
    const float* ow    = (const float*)d_in[2];
    const float* gamma = (const float*)d_in[3];
    const float* beta  = (const float*)d_in[4];
    const float* pi0   = (const float*)d_in[5];
    float* out = (float*)d_out;
    char* ws = (char*)d_ws;

    // workspace layout (bytes):
    short* h_bf   = (short*)(ws);                 // 32MB; reused later as layer_mix
    short* wq_bf  = (short*)(ws + 33554432);      // 8MB
    short* wo_bf  = (short*)(ws + 41943040);      // 2MB
    short* qkv_bf = (short*)(ws + 44040192);      // 128MB; reused later as attn f32 (64MB)
    short* l1     = (short*)(ws + 178257920);     // 32MB
    short* l2     = (short*)(ws + 211812352);     // 32MB  (total ~234MB)
    float* attnf  = (float*)(ws + 44040192);
    short* lmix   = h_bf;

    cvt_bf16<<<16384, 256, 0, stream>>>(h, h_bf, 16777216 / 4);
    cvt_bf16<<<4096, 256, 0, stream>>>(qkvw, wq_bf, 4194304 / 4);
    cvt_bf16<<<1024, 256, 0, stream>>>(ow, wo_bf, 1048576 / 4);

    // qkv = h @ qkv_w^T : [16384, 4096]
    gemm_nt<short><<<dim3(128, 32), 256, 0, stream>>>(h_bf, wq_bf, qkv_bf, 16384, 4096, 1024);

    // fast-weight scan, both memories
    fastweight<<<2048, 256, 0, stream>>>(qkv_bf, l1, l2);

    // pi0-gated mixture + SCALE
    mix_kernel<<<8192, 256, 0, stream>>>(l1, l2, pi0, lmix);

    // attn_out = layer @ o_w^T : [16384, 1024] (fp32 out)
    gemm_nt<float><<<dim3(128, 8), 256, 0, stream>>>(lmix, wo_bf, attnf, 16384, 1024, 1024);

    // x = h + attn_out; LayerNorm
    ln_kernel<<<16384, 256, 0, stream>>>(h, attnf, gamma, beta, out);
}

// Round 2
// 477.040 us; speedup vs baseline: 1.6056x; 1.6056x over previous
//
#include <hip/hip_runtime.h>
#include <type_traits>

// Problem constants: H=16, D=64, DM=1024, L=256, B=64, CHUNK=64, SCALE=1/8.

typedef short v8s __attribute__((ext_vector_type(8)));
typedef float v4f __attribute__((ext_vector_type(4)));

__device__ __forceinline__ float bf2f(short s) {
    unsigned int u = ((unsigned int)(unsigned short)s) << 16;
    float f;
    __builtin_memcpy(&f, &u, 4);
    return f;
}
__device__ __forceinline__ short f2bf(float f) {
    unsigned int u;
    __builtin_memcpy(&u, &f, 4);
    u = u + 0x7fffu + ((u >> 16) & 1u);   // RNE
    return (short)(u >> 16);
}

// ---------------- fp32 -> bf16 conversion (vectorized x4) ----------------
__global__ void __launch_bounds__(256)
cvt_bf16(const float* __restrict__ in, short* __restrict__ out, int n4) {
    int i = blockIdx.x * 256 + threadIdx.x;
    if (i >= n4) return;
    float4 v = ((const float4*)in)[i];
    short4 o;
    o.x = f2bf(v.x); o.y = f2bf(v.y); o.z = f2bf(v.z); o.w = f2bf(v.w);
    ((short4*)out)[i] = o;
}

// ---------------- bf16 MFMA GEMM:  C[M,N] = A[M,K] * B[N,K]^T ----------------
template <typename OutT>
__global__ void __launch_bounds__(256)
gemm_nt(const short* __restrict__ A, const short* __restrict__ B,
        OutT* __restrict__ C, int M, int N, int K) {
    constexpr int BM = 128, BK = 32, LDK = 40;
    __shared__ short sA[BM * LDK];
    __shared__ short sB[BM * LDK];
    const int tid = threadIdx.x;
    const int bm = blockIdx.x, bn = blockIdx.y;
    const int lane = tid & 63, w = tid >> 6;
    const int wy = w >> 1, wx = w & 1;
    const int lr = lane & 15, lq = lane >> 4;

    v4f acc[4][4] = {};

    const int arow = tid >> 1, aseg = (tid & 1) * 16;
    const short* gA = A + (long)(bm * BM + arow) * K + aseg;
    const short* gB = B + (long)(bn * BM + arow) * K + aseg;
    short* lA = &sA[arow * LDK + aseg];
    short* lB = &sB[arow * LDK + aseg];

    for (int kt = 0; kt < K; kt += BK) {
        int4 a0 = *(const int4*)(gA + kt);
        int4 a1 = *(const int4*)(gA + kt + 8);
        int4 b0 = *(const int4*)(gB + kt);
        int4 b1 = *(const int4*)(gB + kt + 8);
        __syncthreads();
        *(int4*)lA = a0; *(int4*)(lA + 8) = a1;
        *(int4*)lB = b0; *(int4*)(lB + 8) = b1;
        __syncthreads();
        v8s af[4], bfv[4];
#pragma unroll
        for (int i = 0; i < 4; i++)
            af[i] = *(const v8s*)&sA[(wy * 64 + i * 16 + lr) * LDK + lq * 8];
#pragma unroll
        for (int j = 0; j < 4; j++)
            bfv[j] = *(const v8s*)&sB[(wx * 64 + j * 16 + lr) * LDK + lq * 8];
#pragma unroll
        for (int i = 0; i < 4; i++)
#pragma unroll
            for (int j = 0; j < 4; j++)
                acc[i][j] = __builtin_amdgcn_mfma_f32_16x16x32_bf16(af[i], bfv[j], acc[i][j], 0, 0, 0);
    }
#pragma unroll
    for (int i = 0; i < 4; i++)
#pragma unroll
        for (int j = 0; j < 4; j++)
#pragma unroll
            for (int r = 0; r < 4; r++) {
                int row = bm * BM + wy * 64 + i * 16 + lq * 4 + r;
                int col = bn * BM + wx * 64 + j * 16 + lr;
                float v = acc[i][j][r];
                if constexpr (std::is_same_v<OutT, short>)
                    C[(long)row * N + col] = f2bf(v);
                else
                    C[(long)row * N + col] = v;
            }
}

// ---------------- fast-weight scan (MFMA bf16) ----------------
// One block per (b, h, mem); 4 waves; per 64-chunk:
//   S = tril(q k^T)   [MFMA, masked on C->LDS writeback]
//   O = S v + q W     [MFMA, K=64+64; W^T read from LDS bf16]
//   W^T += v^T k      [MFMA, fp32 accum resident in registers across chunks]
// LDS matrices stride 72 (16B-aligned rows); XOR-chunk swizzle to cap bank
// conflicts on the transposed b16 scatter writes.
#define SW(row, s) ((row) * 72 + ((((s) >> 3) ^ (((row) >> 4) & 7)) << 3) + ((s) & 7))

__global__ void __launch_bounds__(256)
fastweight(const short* __restrict__ qkv, short* __restrict__ out1, short* __restrict__ out2) {
    const int bid = blockIdx.x;
    const int mem = bid & 1, h = (bid >> 1) & 15, b = bid >> 5;
    const int tid = threadIdx.x;
    const int w = tid >> 6, lane = tid & 63;
    const int lq = lane >> 4, lr = lane & 15;
    __shared__ __align__(16) short sq[64 * 72];
    __shared__ __align__(16) short skS[64 * 72];   // k rows, then S overwrites
    __shared__ __align__(16) short skT[64 * 72];
    __shared__ __align__(16) short svT[64 * 72];
    __shared__ __align__(16) short sWT[64 * 72];
    short* outbuf = mem ? out2 : out1;
    const int koff = 64 + mem * 64;

    for (int i = tid; i < 64 * 36; i += 256) ((int*)sWT)[i] = 0;

    const int r = tid >> 2, seg = (tid & 3) * 16;

    v4f wacc[4] = {};   // persistent W^T slice: rows e'=16w+.., cols d=16n+lr

    for (int c = 0; c < 4; c++) {
        __syncthreads();   // (A) prev-chunk consumers done; sWT writes visible
        const long gbase = ((long)((c * 64 + r) * 64 + b)) * 4096 + h * 256;
        {   // q: phi, row-major
            union { int4 v[2]; short s[16]; } u;
            u.v[0] = *(const int4*)(qkv + gbase + seg);
            u.v[1] = *(const int4*)(qkv + gbase + seg + 8);
            float f[16]; float ssum = 0.f;
#pragma unroll
            for (int i = 0; i < 16; i++) {
                float x = bf2f(u.s[i]);
                float e = x > 0.f ? x + 1.f : __expf(x);
                f[i] = e; ssum += e;
            }
            ssum += __shfl_xor(ssum, 1, 64);
            ssum += __shfl_xor(ssum, 2, 64);
            float inv = 1.f / ssum;
            union { int4 v[2]; short s[16]; } o;
#pragma unroll
            for (int i = 0; i < 16; i++) o.s[i] = f2bf(f[i] * inv);
            *(int4*)&sq[SW(r, seg)] = o.v[0];
            *(int4*)&sq[SW(r, seg + 8)] = o.v[1];
        }
        {   // k: phi, row-major + transposed
            union { int4 v[2]; short s[16]; } u;
            u.v[0] = *(const int4*)(qkv + gbase + koff + seg);
            u.v[1] = *(const int4*)(qkv + gbase + koff + seg + 8);
            float f[16]; float ssum = 0.f;
#pragma unroll
            for (int i = 0; i < 16; i++) {
                float x = bf2f(u.s[i]);
                float e = x > 0.f ? x + 1.f : __expf(x);
                f[i] = e; ssum += e;
            }
            ssum += __shfl_xor(ssum, 1, 64);
            ssum += __shfl_xor(ssum, 2, 64);
            float inv = 1.f / ssum;
            union { int4 v[2]; short s[16]; } o;
#pragma unroll
            for (int i = 0; i < 16; i++) o.s[i] = f2bf(f[i] * inv);
            *(int4*)&skS[SW(r, seg)] = o.v[0];
            *(int4*)&skS[SW(r, seg + 8)] = o.v[1];
#pragma unroll
            for (int i = 0; i < 16; i++) skT[SW(seg + i, r)] = o.s[i];
        }
        {   // v: transposed only
            union { int4 v[2]; short s[16]; } u;
            u.v[0] = *(const int4*)(qkv + gbase + 192 + seg);
            u.v[1] = *(const int4*)(qkv + gbase + 192 + seg + 8);
#pragma unroll
            for (int i = 0; i < 16; i++) svT[SW(seg + i, r)] = u.s[i];
        }
        __syncthreads();   // (B) staging visible

        // q A-frags (rows 16w+lr), reused for S-GEMM and q*W
        v8s qa0 = *(const v8s*)&sq[SW(16 * w + lr, lq * 8)];
        v8s qa1 = *(const v8s*)&sq[SW(16 * w + lr, 32 + lq * 8)];

        // ---- S = q k^T ----
        v4f sacc[4];
#pragma unroll
        for (int n = 0; n < 4; n++) {
            v8s b0 = *(const v8s*)&skS[SW(16 * n + lr, lq * 8)];
            v8s b1 = *(const v8s*)&skS[SW(16 * n + lr, 32 + lq * 8)];
            v4f t = {};
            t = __builtin_amdgcn_mfma_f32_16x16x32_bf16(qa0, b0, t, 0, 0, 0);
            t = __builtin_amdgcn_mfma_f32_16x16x32_bf16(qa1, b1, t, 0, 0, 0);
            sacc[n] = t;
        }
        __syncthreads();   // (C) all waves done reading k rows
        // masked S writeback into skS (own 16-row slice only)
#pragma unroll
        for (int n = 0; n < 4; n++)
#pragma unroll
            for (int rr = 0; rr < 4; rr++) {
                int t_ = 16 * w + lq * 4 + rr;
                int s_ = 16 * n + lr;
                skS[SW(t_, s_)] = f2bf(s_ <= t_ ? sacc[n][rr] : 0.f);
            }

        // ---- O = S v + q W ----
        v8s sa0 = *(const v8s*)&skS[SW(16 * w + lr, lq * 8)];
        v8s sa1 = *(const v8s*)&skS[SW(16 * w + lr, 32 + lq * 8)];
        v4f oacc[4];
#pragma unroll
        for (int n = 0; n < 4; n++) {
            v8s vb0 = *(const v8s*)&svT[SW(16 * n + lr, lq * 8)];
            v8s vb1 = *(const v8s*)&svT[SW(16 * n + lr, 32 + lq * 8)];
            v8s wb0 = *(const v8s*)&sWT[SW(16 * n + lr, lq * 8)];
            v8s wb1 = *(const v8s*)&sWT[SW(16 * n + lr, 32 + lq * 8)];
            v4f t = {};
            t = __builtin_amdgcn_mfma_f32_16x16x32_bf16(sa0, vb0, t, 0, 0, 0);
            t = __builtin_amdgcn_mfma_f32_16x16x32_bf16(sa1, vb1, t, 0, 0, 0);
            t = __builtin_amdgcn_mfma_f32_16x16x32_bf16(qa0, wb0, t, 0, 0, 0);
            t = __builtin_amdgcn_mfma_f32_16x16x32_bf16(qa1, wb1, t, 0, 0, 0);
            oacc[n] = t;
        }
        // epilogue: bf16 scalar stores to global
#pragma unroll
        for (int n = 0; n < 4; n++)
#pragma unroll
            for (int rr = 0; rr < 4; rr++) {
                int t_ = 16 * w + lq * 4 + rr;
                long o = ((long)((c * 64 + t_) * 64 + b)) * 1024 + h * 64 + 16 * n + lr;
                outbuf[o] = f2bf(oacc[n][rr]);
            }

        if (c < 3) {
            __syncthreads();   // (D) all O reads of sWT done before overwrite
            // ---- W^T += v^T k ----
            v8s va0 = *(const v8s*)&svT[SW(16 * w + lr, lq * 8)];
            v8s va1 = *(const v8s*)&svT[SW(16 * w + lr, 32 + lq * 8)];
#pragma unroll
            for (int n = 0; n < 4; n++) {
                v8s kb0 = *(const v8s*)&skT[SW(16 * n + lr, lq * 8)];
                v8s kb1 = *(const v8s*)&skT[SW(16 * n + lr, 32 + lq * 8)];
                wacc[n] = __builtin_amdgcn_mfma_f32_16x16x32_bf16(va0, kb0, wacc[n], 0, 0, 0);
                wacc[n] = __builtin_amdgcn_mfma_f32_16x16x32_bf16(va1, kb1, wacc[n], 0, 0, 0);
            }
            // export W^T slice to LDS bf16 (own rows)
#pragma unroll
            for (int n = 0; n < 4; n++)
#pragma unroll
                for (int rr = 0; rr < 4; rr++)
                    sWT[SW(16 * w + lq * 4 + rr, 16 * n + lr)] = f2bf(wacc[n][rr]);
        }
    }
}

// ---------------- pi0 mixture: lmix = SCALE*(p*l1 + (1-p)*l2), bf16 x8 ----------------
__global__ void __launch_bounds__(256)
mix_kernel(const short* __restrict__ l1, const short* __restrict__ l2,
           const float* __restrict__ pi0, short* __restrict__ outm) {
    long idx8 = ((long)blockIdx.x * 256 + threadIdx.x) * 8;
    int col = (int)(idx8 & 1023);
    int row = (int)(idx8 >> 10);
    int hh = col >> 6;
    int l = row >> 6;   // row = l*B + b, B=64
    float p = pi0[hh * 256 + l];
    p = fminf(fmaxf(p, 0.f), 1.f);
    float q = 1.f - p;
    union { int4 v; short s[8]; } ua, ub, uo;
    ua.v = *(const int4*)(l1 + idx8);
    ub.v = *(const int4*)(l2 + idx8);
#pragma unroll
    for (int i = 0; i < 8; i++)
        uo.s[i] = f2bf(0.125f * (p * bf2f(ua.s[i]) + q * bf2f(ub.s[i])));
    *(int4*)(outm + idx8) = uo.v;
}

// ---------------- residual + LayerNorm over DM=1024 ----------------
__global__ void __launch_bounds__(256)
ln_kernel(const float* __restrict__ h, const float* __restrict__ attn,
          const float* __restrict__ gamma, const float* __restrict__ beta,
          float* __restrict__ out) {
    const int row = blockIdx.x;
    const long base = (long)row * 1024;
    const int tid = threadIdx.x;
    float4 xh = ((const float4*)(h + base))[tid];
    float4 xa = ((const float4*)(attn + base))[tid];
    float4 x;
    x.x = xh.x + xa.x; x.y = xh.y + xa.y; x.z = xh.z + xa.z; x.w = xh.w + xa.w;
    float s = x.x + x.y + x.z + x.w;
    float s2 = x.x * x.x + x.y * x.y + x.z * x.z + x.w * x.w;
#pragma unroll
    for (int m = 32; m > 0; m >>= 1) {
        s += __shfl_xor(s, m, 64);
        s2 += __shfl_xor(s2, m, 64);
    }
    __shared__ float ps[4], ps2[4];
    int w = tid >> 6, lane = tid & 63;
    if (lane == 0) { ps[w] = s; ps2[w] = s2; }
    __syncthreads();
    s = ps[0] + ps[1] + ps[2] + ps[3];
    s2 = ps2[0] + ps2[1] + ps2[2] + ps2[3];
    float mu = s * (1.f / 1024.f);
    float var = s2 * (1.f / 1024.f) - mu * mu;
    float inv = rsqrtf(var + 1e-5f);
    float4 g = ((const float4*)gamma)[tid];
    float4 bb = ((const float4*)beta)[tid];
    float4 o;
    o.x = (x.x - mu) * inv * g.x + bb.x;
    o.y = (x.y - mu) * inv * g.y + bb.y;
    o.z = (x.z - mu) * inv * g.z + bb.z;
    o.w = (x.w - mu) * inv * g.w + bb.w;
    ((float4*)(out + base))[tid] = o;
}

extern "C" void kernel_launch(void* const* d_in, const int* in_sizes, int n_in,
                              void* d_out, int out_size, void* d_ws, size_t ws_size,
                              hipStream_t stream) {
    const float* h     = (const float*)d_in[0];
    const float* qkvw  = (const float*)d_in[1];
    const float* ow    = (const float*)d_in[2];
    const float* gamma = (const float*)d_in[3];
    const float* beta  = (const float*)d_in[4];
    const float* pi0   = (const float*)d_in[5];
    float* out = (float*)d_out;
    char* ws = (char*)d_ws;

    short* h_bf   = (short*)(ws);                 // 32MB; reused later as layer_mix
    short* wq_bf  = (short*)(ws + 33554432);      // 8MB
    short* wo_bf  = (short*)(ws + 41943040);      // 2MB
    short* qkv_bf = (short*)(ws + 44040192);      // 128MB; reused later as attn f32 (64MB)
    short* l1     = (short*)(ws + 178257920);     // 32MB
    short* l2     = (short*)(ws + 211812352);     // 32MB
    float* attnf  = (float*)(ws + 44040192);
    short* lmix   = h_bf;

    cvt_bf16<<<16384, 256, 0, stream>>>(h, h_bf, 16777216 / 4);
    cvt_bf16<<<4096, 256, 0, stream>>>(qkvw, wq_bf, 4194304 / 4);
    cvt_bf16<<<1024, 256, 0, stream>>>(ow, wo_bf, 1048576 / 4);

    gemm_nt<short><<<dim3(128, 32), 256, 0, stream>>>(h_bf, wq_bf, qkv_bf, 16384, 4096, 1024);

    fastweight<<<2048, 256, 0, stream>>>(qkv_bf, l1, l2);

    mix_kernel<<<8192, 256, 0, stream>>>(l1, l2, pi0, lmix);

    gemm_nt<float><<<dim3(128, 8), 256, 0, stream>>>(lmix, wo_bf, attnf, 16384, 1024, 1024);

    ln_kernel<<<16384, 256, 0, stream>>>(h, attnf, gamma, beta, out);
}

// Round 3
// 471.419 us; speedup vs baseline: 1.6248x; 1.0119x over previous
//
#include <hip/hip_runtime.h>
#include <type_traits>

// Problem constants: H=16, D=64, DM=1024, L=256, B=64, CHUNK=64, SCALE=1/8.

typedef short v8s __attribute__((ext_vector_type(8)));
typedef float v4f __attribute__((ext_vector_type(4)));

__device__ __forceinline__ float bf2f(short s) {
    unsigned int u = ((unsigned int)(unsigned short)s) << 16;
    float f;
    __builtin_memcpy(&f, &u, 4);
    return f;
}
__device__ __forceinline__ short f2bf(float f) {
    unsigned int u;
    __builtin_memcpy(&u, &f, 4);
    u = u + 0x7fffu + ((u >> 16) & 1u);   // RNE
    return (short)(u >> 16);
}

// async global->LDS, 16B per lane; LDS dest = wave-uniform base + lane*16
__device__ __forceinline__ void load_lds16(const short* g, short* l) {
    __builtin_amdgcn_global_load_lds((const __attribute__((address_space(1))) void*)g,
                                     (__attribute__((address_space(3))) void*)l, 16, 0, 0);
}

// ---------------- fp32 -> bf16 conversion (vectorized x4) ----------------
__global__ void __launch_bounds__(256)
cvt_bf16(const float* __restrict__ in, short* __restrict__ out, int n4) {
    int i = blockIdx.x * 256 + threadIdx.x;
    if (i >= n4) return;
    float4 v = ((const float4*)in)[i];
    short4 o;
    o.x = f2bf(v.x); o.y = f2bf(v.y); o.z = f2bf(v.z); o.w = f2bf(v.w);
    ((short4*)out)[i] = o;
}

// ---------------- bf16 MFMA GEMM:  C[M,N] = A[M,K] * B[N,K]^T ----------------
// m97 recipe: 128x128 tile, BK=32, unpadded stride-32 LDS, global_load_lds
// width-16 staging. 4 waves (2x2), each wave 64x64 via 4x4 MFMA 16x16x32.
template <typename OutT>
__global__ void __launch_bounds__(256)
gemm_nt(const short* __restrict__ A, const short* __restrict__ B,
        OutT* __restrict__ C, int M, int N, int K) {
    constexpr int BM = 128, BK = 32;
    __shared__ __align__(16) short sA[BM * BK];
    __shared__ __align__(16) short sB[BM * BK];
    const int tid = threadIdx.x;
    const int bm = blockIdx.x, bn = blockIdx.y;
    const int lane = tid & 63, w = tid >> 6;
    const int wy = w >> 1, wx = w & 1;
    const int lr = lane & 15, lq = lane >> 4;

    v4f acc[4][4] = {};

    // staging map: wave w stages rows [32w,32w+32) of each tile, 2 issues/tile.
    // issue j covers rows 32w+16j+(lane>>2), cols (lane&3)*8 .. +8.
    const int srow = 32 * w + (lane >> 2);
    const int scol = (lane & 3) * 8;
    const short* gA0 = A + (long)(bm * BM + srow) * K + scol;
    const short* gB0 = B + (long)(bn * BM + srow) * K + scol;
    short* lA0 = sA + 32 * w * BK;        // wave-uniform
    short* lB0 = sB + 32 * w * BK;

    for (int kt = 0; kt < K; kt += BK) {
        __syncthreads();   // previous iteration's LDS reads done
        load_lds16(gA0 + kt, lA0);
        load_lds16(gA0 + 16 * K + kt, lA0 + 16 * BK);
        load_lds16(gB0 + kt, lB0);
        load_lds16(gB0 + 16 * K + kt, lB0 + 16 * BK);
        __syncthreads();   // staging visible (compiler drains vmcnt here)

        v8s af[4], bfv[4];
#pragma unroll
        for (int i = 0; i < 4; i++)
            af[i] = *(const v8s*)&sA[(wy * 64 + i * 16 + lr) * BK + lq * 8];
#pragma unroll
        for (int j = 0; j < 4; j++)
            bfv[j] = *(const v8s*)&sB[(wx * 64 + j * 16 + lr) * BK + lq * 8];
#pragma unroll
        for (int i = 0; i < 4; i++)
#pragma unroll
            for (int j = 0; j < 4; j++)
                acc[i][j] = __builtin_amdgcn_mfma_f32_16x16x32_bf16(af[i], bfv[j], acc[i][j], 0, 0, 0);
    }
#pragma unroll
    for (int i = 0; i < 4; i++)
#pragma unroll
        for (int j = 0; j < 4; j++)
#pragma unroll
            for (int r = 0; r < 4; r++) {
                int row = bm * BM + wy * 64 + i * 16 + lq * 4 + r;
                int col = bn * BM + wx * 64 + j * 16 + lr;
                float v = acc[i][j][r];
                if constexpr (std::is_same_v<OutT, short>)
                    C[(long)row * N + col] = f2bf(v);
                else
                    C[(long)row * N + col] = v;
            }
}

// ---------------- fast-weight scan (MFMA bf16) ----------------
#define SW(row, s) ((row) * 72 + ((((s) >> 3) ^ (((row) >> 4) & 7)) << 3) + ((s) & 7))

__global__ void __launch_bounds__(256)
fastweight(const short* __restrict__ qkv, short* __restrict__ out1, short* __restrict__ out2) {
    const int bid = blockIdx.x;
    const int mem = bid & 1, h = (bid >> 1) & 15, b = bid >> 5;
    const int tid = threadIdx.x;
    const int w = tid >> 6, lane = tid & 63;
    const int lq = lane >> 4, lr = lane & 15;
    __shared__ __align__(16) short sq[64 * 72];
    __shared__ __align__(16) short skS[64 * 72];   // k rows, then S overwrites
    __shared__ __align__(16) short skT[64 * 72];
    __shared__ __align__(16) short svT[64 * 72];
    __shared__ __align__(16) short sWT[64 * 72];
    short* outbuf = mem ? out2 : out1;
    const int koff = 64 + mem * 64;

    for (int i = tid; i < 64 * 36; i += 256) ((int*)sWT)[i] = 0;

    const int r = tid >> 2, seg = (tid & 3) * 16;

    v4f wacc[4] = {};   // persistent W^T slice

    for (int c = 0; c < 4; c++) {
        __syncthreads();
        const long gbase = ((long)((c * 64 + r) * 64 + b)) * 4096 + h * 256;
        {   // q: phi, row-major
            union { int4 v[2]; short s[16]; } u;
            u.v[0] = *(const int4*)(qkv + gbase + seg);
            u.v[1] = *(const int4*)(qkv + gbase + seg + 8);
            float f[16]; float ssum = 0.f;
#pragma unroll
            for (int i = 0; i < 16; i++) {
                float x = bf2f(u.s[i]);
                float e = x > 0.f ? x + 1.f : __expf(x);
                f[i] = e; ssum += e;
            }
            ssum += __shfl_xor(ssum, 1, 64);
            ssum += __shfl_xor(ssum, 2, 64);
            float inv = 1.f / ssum;
            union { int4 v[2]; short s[16]; } o;
#pragma unroll
            for (int i = 0; i < 16; i++) o.s[i] = f2bf(f[i] * inv);
            *(int4*)&sq[SW(r, seg)] = o.v[0];
            *(int4*)&sq[SW(r, seg + 8)] = o.v[1];
        }
        {   // k: phi, row-major + transposed
            union { int4 v[2]; short s[16]; } u;
            u.v[0] = *(const int4*)(qkv + gbase + koff + seg);
            u.v[1] = *(const int4*)(qkv + gbase + koff + seg + 8);
            float f[16]; float ssum = 0.f;
#pragma unroll
            for (int i = 0; i < 16; i++) {
                float x = bf2f(u.s[i]);
                float e = x > 0.f ? x + 1.f : __expf(x);
                f[i] = e; ssum += e;
            }
            ssum += __shfl_xor(ssum, 1, 64);
            ssum += __shfl_xor(ssum, 2, 64);
            float inv = 1.f / ssum;
            union { int4 v[2]; short s[16]; } o;
#pragma unroll
            for (int i = 0; i < 16; i++) o.s[i] = f2bf(f[i] * inv);
            *(int4*)&skS[SW(r, seg)] = o.v[0];
            *(int4*)&skS[SW(r, seg + 8)] = o.v[1];
#pragma unroll
            for (int i = 0; i < 16; i++) skT[SW(seg + i, r)] = o.s[i];
        }
        {   // v: transposed only
            union { int4 v[2]; short s[16]; } u;
            u.v[0] = *(const int4*)(qkv + gbase + 192 + seg);
            u.v[1] = *(const int4*)(qkv + gbase + 192 + seg + 8);
#pragma unroll
            for (int i = 0; i < 16; i++) svT[SW(seg + i, r)] = u.s[i];
        }
        __syncthreads();

        v8s qa0 = *(const v8s*)&sq[SW(16 * w + lr, lq * 8)];
        v8s qa1 = *(const v8s*)&sq[SW(16 * w + lr, 32 + lq * 8)];

        // ---- S = q k^T ----
        v4f sacc[4];
#pragma unroll
        for (int n = 0; n < 4; n++) {
            v8s b0 = *(const v8s*)&skS[SW(16 * n + lr, lq * 8)];
            v8s b1 = *(const v8s*)&skS[SW(16 * n + lr, 32 + lq * 8)];
            v4f t = {};
            t = __builtin_amdgcn_mfma_f32_16x16x32_bf16(qa0, b0, t, 0, 0, 0);
            t = __builtin_amdgcn_mfma_f32_16x16x32_bf16(qa1, b1, t, 0, 0, 0);
            sacc[n] = t;
        }
        __syncthreads();
#pragma unroll
        for (int n = 0; n < 4; n++)
#pragma unroll
            for (int rr = 0; rr < 4; rr++) {
                int t_ = 16 * w + lq * 4 + rr;
                int s_ = 16 * n + lr;
                skS[SW(t_, s_)] = f2bf(s_ <= t_ ? sacc[n][rr] : 0.f);
            }

        // ---- O = S v + q W ----
        v8s sa0 = *(const v8s*)&skS[SW(16 * w + lr, lq * 8)];
        v8s sa1 = *(const v8s*)&skS[SW(16 * w + lr, 32 + lq * 8)];
        v4f oacc[4];
#pragma unroll
        for (int n = 0; n < 4; n++) {
            v8s vb0 = *(const v8s*)&svT[SW(16 * n + lr, lq * 8)];
            v8s vb1 = *(const v8s*)&svT[SW(16 * n + lr, 32 + lq * 8)];
            v8s wb0 = *(const v8s*)&sWT[SW(16 * n + lr, lq * 8)];
            v8s wb1 = *(const v8s*)&sWT[SW(16 * n + lr, 32 + lq * 8)];
            v4f t = {};
            t = __builtin_amdgcn_mfma_f32_16x16x32_bf16(sa0, vb0, t, 0, 0, 0);
            t = __builtin_amdgcn_mfma_f32_16x16x32_bf16(sa1, vb1, t, 0, 0, 0);
            t = __builtin_amdgcn_mfma_f32_16x16x32_bf16(qa0, wb0, t, 0, 0, 0);
            t = __builtin_amdgcn_mfma_f32_16x16x32_bf16(qa1, wb1, t, 0, 0, 0);
            oacc[n] = t;
        }
#pragma unroll
        for (int n = 0; n < 4; n++)
#pragma unroll
            for (int rr = 0; rr < 4; rr++) {
                int t_ = 16 * w + lq * 4 + rr;
                long o = ((long)((c * 64 + t_) * 64 + b)) * 1024 + h * 64 + 16 * n + lr;
                outbuf[o] = f2bf(oacc[n][rr]);
            }

        if (c < 3) {
            __syncthreads();
            // ---- W^T += v^T k ----
            v8s va0 = *(const v8s*)&svT[SW(16 * w + lr, lq * 8)];
            v8s va1 = *(const v8s*)&svT[SW(16 * w + lr, 32 + lq * 8)];
#pragma unroll
            for (int n = 0; n < 4; n++) {
                v8s kb0 = *(const v8s*)&skT[SW(16 * n + lr, lq * 8)];
                v8s kb1 = *(const v8s*)&skT[SW(16 * n + lr, 32 + lq * 8)];
                wacc[n] = __builtin_amdgcn_mfma_f32_16x16x32_bf16(va0, kb0, wacc[n], 0, 0, 0);
                wacc[n] = __builtin_amdgcn_mfma_f32_16x16x32_bf16(va1, kb1, wacc[n], 0, 0, 0);
            }
#pragma unroll
            for (int n = 0; n < 4; n++)
#pragma unroll
                for (int rr = 0; rr < 4; rr++)
                    sWT[SW(16 * w + lq * 4 + rr, 16 * n + lr)] = f2bf(wacc[n][rr]);
        }
    }
}

// ---------------- pi0 mixture: lmix = SCALE*(p*l1 + (1-p)*l2), bf16 x8 ----------------
__global__ void __launch_bounds__(256)
mix_kernel(const short* __restrict__ l1, const short* __restrict__ l2,
           const float* __restrict__ pi0, short* __restrict__ outm) {
    long idx8 = ((long)blockIdx.x * 256 + threadIdx.x) * 8;
    int col = (int)(idx8 & 1023);
    int row = (int)(idx8 >> 10);
    int hh = col >> 6;
    int l = row >> 6;   // row = l*B + b, B=64
    float p = pi0[hh * 256 + l];
    p = fminf(fmaxf(p, 0.f), 1.f);
    float q = 1.f - p;
    union { int4 v; short s[8]; } ua, ub, uo;
    ua.v = *(const int4*)(l1 + idx8);
    ub.v = *(const int4*)(l2 + idx8);
#pragma unroll
    for (int i = 0; i < 8; i++)
        uo.s[i] = f2bf(0.125f * (p * bf2f(ua.s[i]) + q * bf2f(ub.s[i])));
    *(int4*)(outm + idx8) = uo.v;
}

// ---------------- residual + LayerNorm over DM=1024 ----------------
__global__ void __launch_bounds__(256)
ln_kernel(const float* __restrict__ h, const float* __restrict__ attn,
          const float* __restrict__ gamma, const float* __restrict__ beta,
          float* __restrict__ out) {
    const int row = blockIdx.x;
    const long base = (long)row * 1024;
    const int tid = threadIdx.x;
    float4 xh = ((const float4*)(h + base))[tid];
    float4 xa = ((const float4*)(attn + base))[tid];
    float4 x;
    x.x = xh.x + xa.x; x.y = xh.y + xa.y; x.z = xh.z + xa.z; x.w = xh.w + xa.w;
    float s = x.x + x.y + x.z + x.w;
    float s2 = x.x * x.x + x.y * x.y + x.z * x.z + x.w * x.w;
#pragma unroll
    for (int m = 32; m > 0; m >>= 1) {
        s += __shfl_xor(s, m, 64);
        s2 += __shfl_xor(s2, m, 64);
    }
    __shared__ float ps[4], ps2[4];
    int w = tid >> 6, lane = tid & 63;
    if (lane == 0) { ps[w] = s; ps2[w] = s2; }
    __syncthreads();
    s = ps[0] + ps[1] + ps[2] + ps[3];
    s2 = ps2[0] + ps2[1] + ps2[2] + ps2[3];
    float mu = s * (1.f / 1024.f);
    float var = s2 * (1.f / 1024.f) - mu * mu;
    float inv = rsqrtf(var + 1e-5f);
    float4 g = ((const float4*)gamma)[tid];
    float4 bb = ((const float4*)beta)[tid];
    float4 o;
    o.x = (x.x - mu) * inv * g.x + bb.x;
    o.y = (x.y - mu) * inv * g.y + bb.y;
    o.z = (x.z - mu) * inv * g.z + bb.z;
    o.w = (x.w - mu) * inv * g.w + bb.w;
    ((float4*)(out + base))[tid] = o;
}

extern "C" void kernel_launch(void* const* d_in, const int* in_sizes, int n_in,
                              void* d_out, int out_size, void* d_ws, size_t ws_size,
                              hipStream_t stream) {
    const float* h     = (const float*)d_in[0];
    const float* qkvw  = (const float*)d_in[1];
    const float* ow    = (const float*)d_in[2];
    const float* gamma = (const float*)d_in[3];
    const float* beta  = (const float*)d_in[4];
    const float* pi0   = (const float*)d_in[5];
    float* out = (float*)d_out;
    char* ws = (char*)d_ws;

    short* h_bf   = (short*)(ws);                 // 32MB; reused later as layer_mix
    short* wq_bf  = (short*)(ws + 33554432);      // 8MB
    short* wo_bf  = (short*)(ws + 41943040);      // 2MB
    short* qkv_bf = (short*)(ws + 44040192);      // 128MB; reused later as attn f32 (64MB)
    short* l1     = (short*)(ws + 178257920);     // 32MB
    short* l2     = (short*)(ws + 211812352);     // 32MB
    float* attnf  = (float*)(ws + 44040192);
    short* lmix   = h_bf;

    cvt_bf16<<<16384, 256, 0, stream>>>(h, h_bf, 16777216 / 4);
    cvt_bf16<<<4096, 256, 0, stream>>>(qkvw, wq_bf, 4194304 / 4);
    cvt_bf16<<<1024, 256, 0, stream>>>(ow, wo_bf, 1048576 / 4);

    gemm_nt<short><<<dim3(128, 32), 256, 0, stream>>>(h_bf, wq_bf, qkv_bf, 16384, 4096, 1024);

    fastweight<<<2048, 256, 0, stream>>>(qkv_bf, l1, l2);

    mix_kernel<<<8192, 256, 0, stream>>>(l1, l2, pi0, lmix);

    gemm_nt<float><<<dim3(128, 8), 256, 0, stream>>>(lmix, wo_bf, attnf, 16384, 1024, 1024);

    ln_kernel<<<16384, 256, 0, stream>>>(h, attnf, gamma, beta, out);
}